// Round 2
// baseline (384.716 us; speedup 1.0000x reference)
//
#include <hip/hip_runtime.h>
#include <math.h>

#define NC 80
#define NAA 3
#define TCOLS 6   // targets: [b, cls, x, y, w, h]

// ANCHORS[scale][anchor][wh]
__device__ __constant__ float c_anch[3][3][2] = {
  {{10.f,13.f},{16.f,30.f},{33.f,23.f}},
  {{30.f,61.f},{62.f,45.f},{59.f,119.f}},
  {{116.f,90.f},{156.f,198.f},{373.f,326.f}}
};

// accumulator layout (floats)
#define ACC_BOX    0            // [3] per-scale sum(1-iou)
#define ACC_CLS    3            // [3] per-scale sum(row_sum)
#define ACC_NV     6            // [3] per-scale n_valid
#define ACC_LO     9            // [1] obj loss (already mean-scaled)
#define ACC_SEGSUM 10           // [3*NC]
#define ACC_SEGCNT (10+3*NC)    // [3*NC]
#define ACC_TOTAL  (10+6*NC)

__device__ __forceinline__ float bce(float x, float t) {
  // max(x,0) - x*t + log1p(exp(-|x|))  — matches reference in f32
  return fmaxf(x, 0.f) - x * t + log1pf(expf(-fabsf(x)));
}

__global__ void k_init(unsigned int* mask, int nwords, float* acc, int nacc) {
  int i  = blockIdx.x * blockDim.x + threadIdx.x;
  int st = gridDim.x * blockDim.x;
  for (int k = i; k < nwords; k += st) mask[k] = 0u;
  for (int k = i; k < nacc;   k += st) acc[k]  = 0.f;
}

// one thread per (target, scale): set tobj bits for all 3 anchors (dedup via atomicOr)
__global__ void k_scatter(const float* __restrict__ tgt, int N, int B,
                          unsigned int* __restrict__ mask) {
  int i = blockIdx.x * blockDim.x + threadIdx.x;
  if (i >= N * 3) return;
  int n = i / 3, s = i - n * 3;
  int w = (s == 0) ? 80 : ((s == 1) ? 40 : 20);
  float fw = (float)w;
  float gx = tgt[n*TCOLS + 2] * fw, gy = tgt[n*TCOLS + 3] * fw;
  if (!(gx >= 0.f && gx < fw && gy >= 0.f && gy < fw)) return;  // valid mask
  int gi = min(max((int)floorf(gx), 0), w - 1);
  int gj = min(max((int)floorf(gy), 0), w - 1);
  int b  = min(max((int)tgt[n*TCOLS + 0], 0), B - 1);
  int hw = w * w;
  int base = (s == 0) ? 0 : ((s == 1) ? B*3*6400 : B*3*(6400+1600));
  for (int a = 0; a < 3; ++a) {
    int bit = base + (b*3 + a)*hw + gj*w + gi;
    atomicOr(&mask[bit >> 5], 1u << (bit & 31));
  }
}

// grid-stride over all objectness elements of all 3 scales; bit index == element index
__global__ void k_obj(const float* __restrict__ p0, const float* __restrict__ p1,
                      const float* __restrict__ p2, const unsigned int* __restrict__ mask,
                      float* __restrict__ acc, int B) {
  const int n0 = B*3*6400, n1 = B*3*1600, n2 = B*3*400;
  const int total = n0 + n1 + n2;
  float local = 0.f;
  for (int e = blockIdx.x * blockDim.x + threadIdx.x; e < total;
       e += gridDim.x * blockDim.x) {
    const float* pred; int idx, hw, cnt;
    if (e < n0)           { pred = p0; idx = e;            hw = 6400; cnt = n0; }
    else if (e < n0 + n1) { pred = p1; idx = e - n0;       hw = 1600; cnt = n1; }
    else                  { pred = p2; idx = e - n0 - n1;  hw = 400;  cnt = n2; }
    int ba = idx / hw, pix = idx - ba * hw;
    int b = ba / 3, a = ba - b * 3;
    float x = pred[(size_t)(b*255 + a*85 + 4) * hw + pix];
    float t = (float)((mask[e >> 5] >> (e & 31)) & 1u);
    local += bce(x, t) / (float)cnt;   // per-scale mean, OBJ_GAIN=1
  }
  for (int off = 32; off > 0; off >>= 1) local += __shfl_xor(local, off, 64);
  if ((threadIdx.x & 63) == 0) atomicAdd(&acc[ACC_LO], local);
}

// one 64-lane wave per (scale, target, anchor) row
__global__ void k_rows(const float* __restrict__ p0, const float* __restrict__ p1,
                       const float* __restrict__ p2, const float* __restrict__ tgt,
                       int N, int B, float* __restrict__ acc) {
  int gtid = blockIdx.x * blockDim.x + threadIdx.x;
  int wid  = gtid >> 6;
  int lane = threadIdx.x & 63;
  int nrows = 3 * N * NAA;
  if (wid >= nrows) return;
  int s   = wid / (N * NAA);
  int rem = wid - s * (N * NAA);
  int n   = rem / NAA;
  int a   = rem - n * NAA;
  int w   = (s == 0) ? 80 : ((s == 1) ? 40 : 20);
  int hw  = w * w;
  const float* pred = (s == 0) ? p0 : ((s == 1) ? p1 : p2);
  float fw = (float)w;
  float gx = tgt[n*TCOLS + 2] * fw, gy = tgt[n*TCOLS + 3] * fw;
  if (!(gx >= 0.f && gx < fw && gy >= 0.f && gy < fw)) return;  // mf==0 rows contribute nothing
  float gw = tgt[n*TCOLS + 4] * fw, gh = tgt[n*TCOLS + 5] * fw;
  int gi  = min(max((int)floorf(gx), 0), w - 1);
  int gj  = min(max((int)floorf(gy), 0), w - 1);
  int b   = min(max((int)tgt[n*TCOLS + 0], 0), B - 1);
  int cls = min(max((int)tgt[n*TCOLS + 1], 0), NC - 1);
  size_t base = (size_t)(b*255 + a*85) * hw + (size_t)(gj*w + gi);

  // focal cls loss: lanes cover channels c = lane (NC=80 > 64, lane 0..15 also take lane+64)
  float rs = 0.f;
  for (int c = lane; c < NC; c += 64) {
    float x  = pred[base + (size_t)(5 + c) * hw];
    float t  = (c == cls) ? 1.f : 0.f;
    float ce = bce(x, t);
    float u  = 1.f - expf(-ce);
    rs += u * sqrtf(u) * ce;          // (1-e^-ce)^1.5 * ce
  }
  for (int off = 32; off > 0; off >>= 1) rs += __shfl_xor(rs, off, 64);

  if (lane == 0) {
    float bx = pred[base];
    float by = pred[base + (size_t)hw];
    float bw = pred[base + 2*(size_t)hw];
    float bh = pred[base + 3*(size_t)hw];
    float sx = 1.f/(1.f + expf(-bx));
    float sy = 1.f/(1.f + expf(-by));
    float sw = 1.f/(1.f + expf(-bw));
    float sh = 1.f/(1.f + expf(-bh));
    float px = sx*2.f - 0.5f, py = sy*2.f - 0.5f;
    float aw = c_anch[s][a][0], ah = c_anch[s][a][1];
    float pw = (sw*2.f)*(sw*2.f)*aw, ph = (sh*2.f)*(sh*2.f)*ah;
    float txf = gx - floorf(gx), tyf = gy - floorf(gy);
    // iou_cxcywh, replicated exactly (eps only on heights + union)
    float b1x1 = px - pw*0.5f, b1x2 = px + pw*0.5f;
    float b1y1 = py - ph*0.5f, b1y2 = py + ph*0.5f;
    float b2x1 = txf - gw*0.5f, b2x2 = txf + gw*0.5f;
    float b2y1 = tyf - gh*0.5f, b2y2 = tyf + gh*0.5f;
    float iw = fmaxf(fminf(b1x2, b2x2) - fmaxf(b1x1, b2x1), 0.f);
    float ih = fmaxf(fminf(b1y2, b2y2) - fmaxf(b1y1, b2y1), 0.f);
    float inter = iw * ih;
    float w1 = b1x2 - b1x1, h1 = b1y2 - b1y1 + 1e-7f;
    float w2 = b2x2 - b2x1, h2 = b2y2 - b2y1 + 1e-7f;
    float uni = w1*h1 + w2*h2 - inter + 1e-7f;
    float iou = inter / uni;

    atomicAdd(&acc[ACC_BOX + s], 1.f - iou);
    atomicAdd(&acc[ACC_CLS + s], rs);
    atomicAdd(&acc[ACC_NV  + s], 1.f);
    atomicAdd(&acc[ACC_SEGSUM + s*NC + cls], rs);
    atomicAdd(&acc[ACC_SEGCNT + s*NC + cls], 1.f);
  }
}

__global__ void k_final(const float* __restrict__ acc, float* __restrict__ out) {
  int t = threadIdx.x;
  if (t == 0) {
    float lb = 0.f, lc = 0.f;
    for (int s = 0; s < 3; ++s) {
      float nv  = acc[ACC_NV + s];
      float nvm = fmaxf(nv, 1.f);
      if (nv > 0.f) {
        lb += acc[ACC_BOX + s] / nvm * 7.5f;                 // BOX_GAIN
        lc += acc[ACC_CLS + s] / (nvm * (float)NC) * 0.5f;   // CLS_GAIN
      }
    }
    float lo = acc[ACC_LO];                                   // OBJ_GAIN = 1
    out[0] = lb + lc + lo;
    out[1] = lb;
    out[2] = lc;
    out[3] = lo;
  }
  if (t < NC) {
    float pc = 0.f;
    for (int s = 0; s < 3; ++s) {
      float cnt = acc[ACC_SEGCNT + s*NC + t];
      if (cnt > 0.f)
        pc += acc[ACC_SEGSUM + s*NC + t] / (fmaxf(cnt, 1.f) * (float)NC) * 0.5f;
    }
    out[4 + t] = pc;
  }
}

extern "C" void kernel_launch(void* const* d_in, const int* in_sizes, int n_in,
                              void* d_out, int out_size, void* d_ws, size_t ws_size,
                              hipStream_t stream) {
  const float* p0  = (const float*)d_in[0];
  const float* p1  = (const float*)d_in[1];
  const float* p2  = (const float*)d_in[2];
  const float* tgt = (const float*)d_in[3];
  int N = in_sizes[3] / TCOLS;             // 800 targets (6 cols: b,cls,x,y,w,h)
  int B = in_sizes[0] / (255 * 6400);      // 16
  float* out = (float*)d_out;

  unsigned int* mask = (unsigned int*)d_ws;
  int nbits  = B * 3 * (6400 + 1600 + 400);        // 403,200 tobj cells
  int nwords = (nbits + 31) / 32;                  // 12,600 words (50.4 KB)
  float* acc = (float*)((char*)d_ws + (((size_t)nwords * 4 + 255) & ~(size_t)255));

  k_init<<<64, 256, 0, stream>>>(mask, nwords, acc, ACC_TOTAL);
  k_scatter<<<(N*3 + 255)/256, 256, 0, stream>>>(tgt, N, B, mask);
  k_obj<<<(nbits + 255)/256, 256, 0, stream>>>(p0, p1, p2, mask, acc, B);
  int nrows = 3 * N * NAA;                          // 7200 waves
  k_rows<<<(nrows*64 + 255)/256, 256, 0, stream>>>(p0, p1, p2, tgt, N, B, acc);
  k_final<<<1, 128, 0, stream>>>(acc, out);
}

// Round 3
// 49.284 us; speedup vs baseline: 7.8061x; 7.8061x over previous
//
#include <hip/hip_runtime.h>
#include <math.h>

#define NC 80
#define NAA 3
#define TCOLS 6   // targets: [b, cls, x, y, w, h]

// ANCHORS[scale][anchor][wh]
__device__ __constant__ float c_anch[3][3][2] = {
  {{10.f,13.f},{16.f,30.f},{33.f,23.f}},
  {{30.f,61.f},{62.f,45.f},{59.f,119.f}},
  {{116.f,90.f},{156.f,198.f},{373.f,326.f}}
};

// accumulator layout (floats) — each hot scalar gets its own 64 B cache line
#define ACC_LO     0                    // [1] obj loss (line 0)
#define ACC_BOX(s) (16 + 16*(s))        // lines 1..3
#define ACC_CLS(s) (64 + 16*(s))        // lines 4..6
#define ACC_NV(s)  (112 + 16*(s))       // lines 7..9
#define ACC_SEG    160                  // segsum[3*NC], then segcnt[3*NC]
#define ACC_TOTAL  (160 + 6*NC)         // 640 floats

__device__ __forceinline__ float bce(float x, float t) {
  // max(x,0) - x*t + log1p(exp(-|x|))  — matches reference in f32
  return fmaxf(x, 0.f) - x * t + log1pf(expf(-fabsf(x)));
}

__global__ void k_init(unsigned int* mask, int nwords, float* acc, int nacc) {
  int i  = blockIdx.x * blockDim.x + threadIdx.x;
  int st = gridDim.x * blockDim.x;
  for (int k = i; k < nwords; k += st) mask[k] = 0u;
  for (int k = i; k < nacc;   k += st) acc[k]  = 0.f;
}

// one thread per (target, scale): set tobj bits for all 3 anchors (dedup via atomicOr)
__global__ void k_scatter(const float* __restrict__ tgt, int N, int B,
                          unsigned int* __restrict__ mask) {
  int i = blockIdx.x * blockDim.x + threadIdx.x;
  if (i >= N * 3) return;
  int n = i / 3, s = i - n * 3;
  int w = (s == 0) ? 80 : ((s == 1) ? 40 : 20);
  float fw = (float)w;
  float gx = tgt[n*TCOLS + 2] * fw, gy = tgt[n*TCOLS + 3] * fw;
  if (!(gx >= 0.f && gx < fw && gy >= 0.f && gy < fw)) return;  // valid mask
  int gi = min(max((int)floorf(gx), 0), w - 1);
  int gj = min(max((int)floorf(gy), 0), w - 1);
  int b  = min(max((int)tgt[n*TCOLS + 0], 0), B - 1);
  int hw = w * w;
  int base = (s == 0) ? 0 : ((s == 1) ? B*3*6400 : B*3*(6400+1600));
  for (int a = 0; a < 3; ++a) {
    int bit = base + (b*3 + a)*hw + gj*w + gi;
    atomicOr(&mask[bit >> 5], 1u << (bit & 31));
  }
}

// float4 over all objectness elements; block-reduced, ONE global atomic per block
__global__ void k_obj(const float* __restrict__ p0, const float* __restrict__ p1,
                      const float* __restrict__ p2, const unsigned int* __restrict__ mask,
                      float* __restrict__ acc, int B) {
  const int n0 = B*3*6400, n1 = B*3*1600, n2 = B*3*400;
  const int total4 = (n0 + n1 + n2) >> 2;          // hw's all divisible by 4
  float local = 0.f;
  int i = blockIdx.x * blockDim.x + threadIdx.x;
  if (i < total4) {
    int e = i << 2;
    const float* pred; int idx, hw, cnt;
    if (e < n0)           { pred = p0; idx = e;            hw = 6400; cnt = n0; }
    else if (e < n0 + n1) { pred = p1; idx = e - n0;       hw = 1600; cnt = n1; }
    else                  { pred = p2; idx = e - n0 - n1;  hw = 400;  cnt = n2; }
    int ba = idx / hw, pix = idx - ba * hw;        // pix..pix+3 stay in-plane (hw%4==0)
    int b = ba / 3, a = ba - b * 3;
    const float4 x4 = *(const float4*)&pred[(size_t)(b*255 + a*85 + 4) * hw + pix];
    unsigned mw = mask[e >> 5];                    // bits e..e+3 share one word (e%4==0)
    int sh = e & 31;
    float inv = 1.f / (float)cnt;
    local += bce(x4.x, (float)((mw >> (sh+0)) & 1u)) * inv;
    local += bce(x4.y, (float)((mw >> (sh+1)) & 1u)) * inv;
    local += bce(x4.z, (float)((mw >> (sh+2)) & 1u)) * inv;
    local += bce(x4.w, (float)((mw >> (sh+3)) & 1u)) * inv;
  }
  for (int off = 32; off > 0; off >>= 1) local += __shfl_xor(local, off, 64);
  __shared__ float red[4];
  int lane = threadIdx.x & 63, wv = threadIdx.x >> 6;
  if (lane == 0) red[wv] = local;
  __syncthreads();
  if (threadIdx.x == 0)
    atomicAdd(&acc[ACC_LO], red[0] + red[1] + red[2] + red[3]);
}

// one 64-lane wave per (scale, target, anchor) row; block-level LDS pre-reduce
__global__ void k_rows(const float* __restrict__ p0, const float* __restrict__ p1,
                       const float* __restrict__ p2, const float* __restrict__ tgt,
                       int N, int B, float* __restrict__ acc) {
  __shared__ float l_box[3], l_cls[3], l_nv[3];
  if (threadIdx.x < 3) { l_box[threadIdx.x] = 0.f; l_cls[threadIdx.x] = 0.f; l_nv[threadIdx.x] = 0.f; }
  __syncthreads();

  int gtid = blockIdx.x * blockDim.x + threadIdx.x;
  int wid  = gtid >> 6;
  int lane = threadIdx.x & 63;
  int nrows = 3 * N * NAA;
  if (wid < nrows) {
    int s   = wid / (N * NAA);
    int rem = wid - s * (N * NAA);
    int n   = rem / NAA;
    int a   = rem - n * NAA;
    int w   = (s == 0) ? 80 : ((s == 1) ? 40 : 20);
    int hw  = w * w;
    const float* pred = (s == 0) ? p0 : ((s == 1) ? p1 : p2);
    float fw = (float)w;
    float gx = tgt[n*TCOLS + 2] * fw, gy = tgt[n*TCOLS + 3] * fw;
    if (gx >= 0.f && gx < fw && gy >= 0.f && gy < fw) {   // mf==1 rows only
      float gw = tgt[n*TCOLS + 4] * fw, gh = tgt[n*TCOLS + 5] * fw;
      int gi  = min(max((int)floorf(gx), 0), w - 1);
      int gj  = min(max((int)floorf(gy), 0), w - 1);
      int b   = min(max((int)tgt[n*TCOLS + 0], 0), B - 1);
      int cls = min(max((int)tgt[n*TCOLS + 1], 0), NC - 1);
      size_t base = (size_t)(b*255 + a*85) * hw + (size_t)(gj*w + gi);

      // focal cls loss: lanes cover channels c = lane (+64 for lanes 0..15)
      float rs = 0.f;
      for (int c = lane; c < NC; c += 64) {
        float x  = pred[base + (size_t)(5 + c) * hw];
        float t  = (c == cls) ? 1.f : 0.f;
        float ce = bce(x, t);
        float u  = 1.f - expf(-ce);
        rs += u * sqrtf(u) * ce;          // (1-e^-ce)^1.5 * ce
      }
      for (int off = 32; off > 0; off >>= 1) rs += __shfl_xor(rs, off, 64);

      if (lane == 0) {
        float bx = pred[base];
        float by = pred[base + (size_t)hw];
        float bw = pred[base + 2*(size_t)hw];
        float bh = pred[base + 3*(size_t)hw];
        float sx = 1.f/(1.f + expf(-bx));
        float sy = 1.f/(1.f + expf(-by));
        float sw = 1.f/(1.f + expf(-bw));
        float sh = 1.f/(1.f + expf(-bh));
        float px = sx*2.f - 0.5f, py = sy*2.f - 0.5f;
        float aw = c_anch[s][a][0], ah = c_anch[s][a][1];
        float pw = (sw*2.f)*(sw*2.f)*aw, ph = (sh*2.f)*(sh*2.f)*ah;
        float txf = gx - floorf(gx), tyf = gy - floorf(gy);
        // iou_cxcywh, replicated exactly (eps only on heights + union)
        float b1x1 = px - pw*0.5f, b1x2 = px + pw*0.5f;
        float b1y1 = py - ph*0.5f, b1y2 = py + ph*0.5f;
        float b2x1 = txf - gw*0.5f, b2x2 = txf + gw*0.5f;
        float b2y1 = tyf - gh*0.5f, b2y2 = tyf + gh*0.5f;
        float iw = fmaxf(fminf(b1x2, b2x2) - fmaxf(b1x1, b2x1), 0.f);
        float ih = fmaxf(fminf(b1y2, b2y2) - fmaxf(b1y1, b2y1), 0.f);
        float inter = iw * ih;
        float w1 = b1x2 - b1x1, h1 = b1y2 - b1y1 + 1e-7f;
        float w2 = b2x2 - b2x1, h2 = b2y2 - b2y1 + 1e-7f;
        float uni = w1*h1 + w2*h2 - inter + 1e-7f;
        float iou = inter / uni;

        atomicAdd(&l_box[s], 1.f - iou);       // LDS atomics (cheap)
        atomicAdd(&l_cls[s], rs);
        atomicAdd(&l_nv[s],  1.f);
        // seg buckets: 480 addresses spread over many lines — low contention
        atomicAdd(&acc[ACC_SEG +        s*NC + cls], rs);
        atomicAdd(&acc[ACC_SEG + 3*NC + s*NC + cls], 1.f);
      }
    }
  }
  __syncthreads();
  if (threadIdx.x < 3) {
    float v;
    v = l_box[threadIdx.x]; if (v != 0.f) atomicAdd(&acc[ACC_BOX(threadIdx.x)], v);
    v = l_cls[threadIdx.x]; if (v != 0.f) atomicAdd(&acc[ACC_CLS(threadIdx.x)], v);
    v = l_nv [threadIdx.x]; if (v != 0.f) atomicAdd(&acc[ACC_NV (threadIdx.x)], v);
  }
}

__global__ void k_final(const float* __restrict__ acc, float* __restrict__ out) {
  int t = threadIdx.x;
  if (t == 0) {
    float lb = 0.f, lc = 0.f;
    for (int s = 0; s < 3; ++s) {
      float nv  = acc[ACC_NV(s)];
      float nvm = fmaxf(nv, 1.f);
      if (nv > 0.f) {
        lb += acc[ACC_BOX(s)] / nvm * 7.5f;                 // BOX_GAIN
        lc += acc[ACC_CLS(s)] / (nvm * (float)NC) * 0.5f;   // CLS_GAIN
      }
    }
    float lo = acc[ACC_LO];                                  // OBJ_GAIN = 1
    out[0] = lb + lc + lo;
    out[1] = lb;
    out[2] = lc;
    out[3] = lo;
  }
  if (t < NC) {
    float pc = 0.f;
    for (int s = 0; s < 3; ++s) {
      float cnt = acc[ACC_SEG + 3*NC + s*NC + t];
      if (cnt > 0.f)
        pc += acc[ACC_SEG + s*NC + t] / (fmaxf(cnt, 1.f) * (float)NC) * 0.5f;
    }
    out[4 + t] = pc;
  }
}

extern "C" void kernel_launch(void* const* d_in, const int* in_sizes, int n_in,
                              void* d_out, int out_size, void* d_ws, size_t ws_size,
                              hipStream_t stream) {
  const float* p0  = (const float*)d_in[0];
  const float* p1  = (const float*)d_in[1];
  const float* p2  = (const float*)d_in[2];
  const float* tgt = (const float*)d_in[3];
  int N = in_sizes[3] / TCOLS;             // 800 targets (6 cols: b,cls,x,y,w,h)
  int B = in_sizes[0] / (255 * 6400);      // 16
  float* out = (float*)d_out;

  unsigned int* mask = (unsigned int*)d_ws;
  int nbits  = B * 3 * (6400 + 1600 + 400);        // 403,200 tobj cells
  int nwords = (nbits + 31) / 32;                  // 12,600 words (50.4 KB)
  float* acc = (float*)((char*)d_ws + (((size_t)nwords * 4 + 255) & ~(size_t)255));

  k_init<<<64, 256, 0, stream>>>(mask, nwords, acc, ACC_TOTAL);
  k_scatter<<<(N*3 + 255)/256, 256, 0, stream>>>(tgt, N, B, mask);
  int total4 = nbits / 4;
  k_obj<<<(total4 + 255)/256, 256, 0, stream>>>(p0, p1, p2, mask, acc, B);
  int nrows = 3 * N * NAA;                          // 7200 waves
  k_rows<<<(nrows*64 + 255)/256, 256, 0, stream>>>(p0, p1, p2, tgt, N, B, acc);
  k_final<<<1, 128, 0, stream>>>(acc, out);
}

// Round 4
// 43.489 us; speedup vs baseline: 8.8463x; 1.1333x over previous
//
#include <hip/hip_runtime.h>
#include <math.h>

#define NC 80
#define TCOLS 6   // targets: [b, cls, x, y, w, h]

// ANCHORS[scale][anchor][wh]
__device__ __constant__ float c_anch[3][3][2] = {
  {{10.f,13.f},{16.f,30.f},{33.f,23.f}},
  {{30.f,61.f},{62.f,45.f},{59.f,119.f}},
  {{116.f,90.f},{156.f,198.f},{373.f,326.f}}
};

// acc layout (floats) — each hot scalar on its own 64 B line
#define ACC_CORR   0                    // obj correction  sum(-x/cnt)
#define ACC_BOX(s) (16 + 16*(s))
#define ACC_CLS(s) (64 + 16*(s))
#define ACC_NV(s)  (112 + 16*(s))
#define ACC_SEG    160                  // segsum[3*NC], then segcnt[3*NC]
#define ACC_TOTAL  (160 + 6*NC)         // 640 floats

__device__ __forceinline__ float bce0(float x) {   // bce(x, 0)
  return fmaxf(x, 0.f) + log1pf(expf(-fabsf(x)));
}
__device__ __forceinline__ float bce(float x, float t) {
  return fmaxf(x, 0.f) - x * t + log1pf(expf(-fabsf(x)));
}
__device__ __forceinline__ float focal(float x, float t) {
  float ce = bce(x, t);
  float u  = 1.f - expf(-ce);
  return u * sqrtf(u) * ce;            // (1-e^-ce)^1.5 * ce
}

// Fused: zero mask+acc, stream-reduce bce(pobj,0) -> per-block partials (no atomics)
__global__ void k_obj(const float* __restrict__ p0, const float* __restrict__ p1,
                      const float* __restrict__ p2, unsigned int* __restrict__ mask,
                      int nwords, float* __restrict__ acc,
                      float* __restrict__ partial, int B) {
  int tid    = blockIdx.x * blockDim.x + threadIdx.x;
  int stride = gridDim.x * blockDim.x;
  for (int k = tid; k < nwords;    k += stride) mask[k] = 0u;
  for (int k = tid; k < ACC_TOTAL; k += stride) acc[k]  = 0.f;

  const int n0 = B*3*6400, n1 = B*3*1600, n2 = B*3*400;
  const int total4 = (n0 + n1 + n2) >> 2;
  const float i0 = 1.f/(float)n0, i1 = 1.f/(float)n1, i2 = 1.f/(float)n2;
  float local = 0.f;
  for (int i = tid; i < total4; i += stride) {
    int e = i << 2;
    const float* pred; int idx, hw; float inv;
    if (e < n0)         { pred = p0; idx = e;           hw = 6400; inv = i0; }
    else if (e < n0+n1) { pred = p1; idx = e - n0;      hw = 1600; inv = i1; }
    else                { pred = p2; idx = e - n0 - n1; hw = 400;  inv = i2; }
    int ba = idx / hw, pix = idx - ba * hw;       // pix..pix+3 in-plane (hw%4==0)
    int b = ba / 3, a = ba - b * 3;
    const float4 x4 = *(const float4*)&pred[(size_t)(b*255 + a*85 + 4) * hw + pix];
    local += (bce0(x4.x) + bce0(x4.y) + bce0(x4.z) + bce0(x4.w)) * inv;
  }
  for (int off = 32; off > 0; off >>= 1) local += __shfl_xor(local, off, 64);
  __shared__ float red[4];
  if ((threadIdx.x & 63) == 0) red[threadIdx.x >> 6] = local;
  __syncthreads();
  if (threadIdx.x == 0) partial[blockIdx.x] = red[0] + red[1] + red[2] + red[3];
}

// blocks [0, RB): one 64-lane wave per (scale,target,anchor) row, 16 rows/block.
// blocks [RB, RB+SB): tobj scatter + dedup'd obj correction (bce(x,1)-bce(x,0) = -x).
__global__ void k_rows(const float* __restrict__ p0, const float* __restrict__ p1,
                       const float* __restrict__ p2, const float* __restrict__ tgt,
                       unsigned int* __restrict__ mask, int N, int B, int RB,
                       float* __restrict__ acc) {
  __shared__ float l_box[3], l_cls[3], l_nv[3];
  __shared__ float lred[16];
  int bid = blockIdx.x;

  if (bid < RB) {
    if (threadIdx.x < 3) { l_box[threadIdx.x]=0.f; l_cls[threadIdx.x]=0.f; l_nv[threadIdx.x]=0.f; }
    __syncthreads();
    int row   = bid * 16 + (threadIdx.x >> 6);
    int lane  = threadIdx.x & 63;
    int nrows = 3 * N * 3;
    if (row < nrows) {
      int rps = N * 3;
      int s   = row / rps;
      int rem = row - s * rps;
      int n   = rem / 3;
      int a   = rem - n * 3;
      int w   = (s == 0) ? 80 : ((s == 1) ? 40 : 20);
      int hw  = w * w;
      const float* pred = (s == 0) ? p0 : ((s == 1) ? p1 : p2);
      float fw = (float)w;
      float gx = tgt[n*TCOLS + 2] * fw, gy = tgt[n*TCOLS + 3] * fw;
      if (gx >= 0.f && gx < fw && gy >= 0.f && gy < fw) {   // wave-uniform branch
        float gw = tgt[n*TCOLS + 4] * fw, gh = tgt[n*TCOLS + 5] * fw;
        int gi  = min(max((int)floorf(gx), 0), w - 1);
        int gj  = min(max((int)floorf(gy), 0), w - 1);
        int b   = min(max((int)tgt[n*TCOLS + 0], 0), B - 1);
        int cls = min(max((int)tgt[n*TCOLS + 1], 0), NC - 1);
        size_t base = (size_t)(b*255 + a*85) * hw + (size_t)(gj*w + gi);

        // issue ALL global loads before any use (MLP):
        float x0  = pred[base + (size_t)(5 + lane) * hw];          // cls c = lane
        float x1  = pred[base + (size_t)(69 + (lane & 15)) * hw];  // cls c = 64+(lane&15), dup-coalesced
        float bxv = (lane < 4) ? pred[base + (size_t)lane * hw] : 0.f;  // box ch on lanes 0..3

        float rs = focal(x0, (lane == cls) ? 1.f : 0.f);
        if (lane < 16) rs += focal(x1, ((64 + lane) == cls) ? 1.f : 0.f);
        for (int off = 32; off > 0; off >>= 1) rs += __shfl_xor(rs, off, 64);

        float bx = __shfl(bxv, 0, 64), by = __shfl(bxv, 1, 64);
        float bw = __shfl(bxv, 2, 64), bh = __shfl(bxv, 3, 64);
        if (lane == 0) {
          float sx = 1.f/(1.f + expf(-bx));
          float sy = 1.f/(1.f + expf(-by));
          float sw = 1.f/(1.f + expf(-bw));
          float sh = 1.f/(1.f + expf(-bh));
          float px = sx*2.f - 0.5f, py = sy*2.f - 0.5f;
          float aw = c_anch[s][a][0], ah = c_anch[s][a][1];
          float pw = (sw*2.f)*(sw*2.f)*aw, ph = (sh*2.f)*(sh*2.f)*ah;
          float txf = gx - floorf(gx), tyf = gy - floorf(gy);
          // iou_cxcywh replicated exactly (eps on heights + union only)
          float b1x1 = px - pw*0.5f, b1x2 = px + pw*0.5f;
          float b1y1 = py - ph*0.5f, b1y2 = py + ph*0.5f;
          float b2x1 = txf - gw*0.5f, b2x2 = txf + gw*0.5f;
          float b2y1 = tyf - gh*0.5f, b2y2 = tyf + gh*0.5f;
          float iw = fmaxf(fminf(b1x2, b2x2) - fmaxf(b1x1, b2x1), 0.f);
          float ih = fmaxf(fminf(b1y2, b2y2) - fmaxf(b1y1, b2y1), 0.f);
          float inter = iw * ih;
          float w1 = b1x2 - b1x1, h1 = b1y2 - b1y1 + 1e-7f;
          float w2 = b2x2 - b2x1, h2 = b2y2 - b2y1 + 1e-7f;
          float uni = w1*h1 + w2*h2 - inter + 1e-7f;
          float iou = inter / uni;

          atomicAdd(&l_box[s], 1.f - iou);   // LDS pre-reduce
          atomicAdd(&l_cls[s], rs);
          atomicAdd(&l_nv[s],  1.f);
          atomicAdd(&acc[ACC_SEG +        s*NC + cls], rs);   // ~60 lines, low contention
          atomicAdd(&acc[ACC_SEG + 3*NC + s*NC + cls], 1.f);
        }
      }
    }
    __syncthreads();
    if (threadIdx.x < 3) {
      int s = threadIdx.x; float v;
      v = l_box[s]; if (v != 0.f) atomicAdd(&acc[ACC_BOX(s)], v);
      v = l_cls[s]; if (v != 0.f) atomicAdd(&acc[ACC_CLS(s)], v);
      v = l_nv [s]; if (v != 0.f) atomicAdd(&acc[ACC_NV (s)], v);
    }
  } else {
    // ---- scatter + correction path ----
    int i = (bid - RB) * blockDim.x + threadIdx.x;
    float corr = 0.f;
    if (i < N * 3) {
      int n = i / 3, s = i - n * 3;
      int w = (s == 0) ? 80 : ((s == 1) ? 40 : 20);
      float fw = (float)w;
      float gx = tgt[n*TCOLS + 2] * fw, gy = tgt[n*TCOLS + 3] * fw;
      if (gx >= 0.f && gx < fw && gy >= 0.f && gy < fw) {
        int hw = w * w;
        int gi = min(max((int)floorf(gx), 0), w - 1);
        int gj = min(max((int)floorf(gy), 0), w - 1);
        int b  = min(max((int)tgt[n*TCOLS + 0], 0), B - 1);
        const float* pred = (s == 0) ? p0 : ((s == 1) ? p1 : p2);
        int basebit = (s == 0) ? 0 : ((s == 1) ? B*3*6400 : B*3*8000);
        float inv = 1.f / (float)(B*3*hw);
        for (int a = 0; a < 3; ++a) {
          int bit = basebit + (b*3 + a)*hw + gj*w + gi;
          unsigned int m = 1u << (bit & 31);
          unsigned int old = atomicOr(&mask[bit >> 5], m);
          if (!(old & m)) {   // this thread newly set the bit -> owns the correction
            float x = pred[(size_t)(b*255 + a*85 + 4) * hw + (size_t)(gj*w + gi)];
            corr -= x * inv;  // bce(x,1) - bce(x,0) = -x
          }
        }
      }
    }
    for (int off = 32; off > 0; off >>= 1) corr += __shfl_xor(corr, off, 64);
    if ((threadIdx.x & 63) == 0) lred[threadIdx.x >> 6] = corr;
    __syncthreads();
    if (threadIdx.x == 0) {
      float t = 0.f;
      for (int k = 0; k < (int)(blockDim.x >> 6); ++k) t += lred[k];
      if (t != 0.f) atomicAdd(&acc[ACC_CORR], t);
    }
  }
}

__global__ void k_final(const float* __restrict__ acc, const float* __restrict__ partial,
                        float* __restrict__ out) {
  __shared__ float slo[2];
  int t = threadIdx.x;                       // 128 threads
  float v = partial[t] + partial[t + 128];
  for (int off = 32; off > 0; off >>= 1) v += __shfl_xor(v, off, 64);
  if ((t & 63) == 0) slo[t >> 6] = v;
  __syncthreads();
  if (t == 0) {
    float lo = slo[0] + slo[1] + acc[ACC_CORR];   // stream part + dedup'd correction
    float lb = 0.f, lc = 0.f;
    for (int s = 0; s < 3; ++s) {
      float nv  = acc[ACC_NV(s)];
      float nvm = fmaxf(nv, 1.f);
      if (nv > 0.f) {
        lb += acc[ACC_BOX(s)] / nvm * 7.5f;                 // BOX_GAIN
        lc += acc[ACC_CLS(s)] / (nvm * (float)NC) * 0.5f;   // CLS_GAIN
      }
    }
    out[0] = lb + lc + lo;
    out[1] = lb;
    out[2] = lc;
    out[3] = lo;
  }
  if (t < NC) {
    float pc = 0.f;
    for (int s = 0; s < 3; ++s) {
      float cnt = acc[ACC_SEG + 3*NC + s*NC + t];
      if (cnt > 0.f)
        pc += acc[ACC_SEG + s*NC + t] / (fmaxf(cnt, 1.f) * (float)NC) * 0.5f;
    }
    out[4 + t] = pc;
  }
}

extern "C" void kernel_launch(void* const* d_in, const int* in_sizes, int n_in,
                              void* d_out, int out_size, void* d_ws, size_t ws_size,
                              hipStream_t stream) {
  const float* p0  = (const float*)d_in[0];
  const float* p1  = (const float*)d_in[1];
  const float* p2  = (const float*)d_in[2];
  const float* tgt = (const float*)d_in[3];
  int N = in_sizes[3] / TCOLS;             // 800 targets
  int B = in_sizes[0] / (255 * 6400);      // 16
  float* out = (float*)d_out;

  unsigned int* mask = (unsigned int*)d_ws;
  int nbits  = B * 3 * (6400 + 1600 + 400);            // 403,200 tobj cells
  int nwords = (nbits + 31) / 32;                      // 12,600 words
  float* acc     = (float*)((char*)d_ws + (((size_t)nwords * 4 + 255) & ~(size_t)255));
  float* partial = acc + ACC_TOTAL;                    // 256 per-block obj partials

  k_obj<<<256, 256, 0, stream>>>(p0, p1, p2, mask, nwords, acc, partial, B);
  int nrows = 3 * N * 3;                               // 7200 rows
  int RB = (nrows + 15) / 16;                          // 450 row-blocks (16 waves each)
  int SB = (N*3 + 1023) / 1024;                        // 3 scatter-blocks
  k_rows<<<RB + SB, 1024, 0, stream>>>(p0, p1, p2, tgt, mask, N, B, RB, acc);
  k_final<<<1, 128, 0, stream>>>(acc, partial, out);
}